// Round 4
// baseline (340.729 us; speedup 1.0000x reference)
//
#include <hip/hip_runtime.h>
#include <math.h>

#define L_ 200

// ============================================================================
// K1: pooling, 2 waves per row with MOD-2 INTERLEAVED token split (balanced:
// each wave does ceil/floor(len/2) gathers regardless of len), 4-deep gather
// ILP (verified structure). Blocks 0..63 also transpose-pack W1. Block 0
// zeroes the completion counters used by K2/K3 (ws is poisoned between reps).
// ============================================================================
__global__ __launch_bounds__(256) void pool_pack_kernel(
    const int* __restrict__ tokens, const int* __restrict__ lengths,
    const float* __restrict__ emb, float* __restrict__ pooled,
    const float* __restrict__ W1, float* __restrict__ W1p,
    int* __restrict__ cnts) {
  const int tid = threadIdx.x;
  if (blockIdx.x == 0 && tid < 8) cnts[tid] = 0;   // K2/K3 counters
  if (blockIdx.x < 64) {
    float4 v = ((const float4*)W1)[tid * 64 + blockIdx.x];
    ((float4*)W1p)[blockIdx.x * 256 + tid] = v;
  }
  const int wv = tid >> 6, lane = tid & 63;
  const int row = blockIdx.x * 2 + (wv >> 1);
  const int half = wv & 1;
  const int len = lengths[row];
  const int cnt = (len + 1 - half) >> 1;   // tokens with index%2 == half
  const int* trow = tokens + row * L_;
  const float4* embv = (const float4*)emb;   // emb row = 64 float4
  float4 a0 = make_float4(0.f, 0.f, 0.f, 0.f);
  float4 a1 = a0, a2 = a0, a3 = a0;
  for (int b0 = 0; b0 < cnt; b0 += 64) {
    int nt = cnt - b0; nt = nt > 64 ? 64 : nt;
    int tk = (lane < nt) ? trow[half + 2 * (b0 + lane)] : 0;  // stride-2 load
    int j = 0;
    for (; j + 4 <= nt; j += 4) {
      int t0 = __shfl(tk, j);
      int t1 = __shfl(tk, j + 1);
      int t2 = __shfl(tk, j + 2);
      int t3 = __shfl(tk, j + 3);
      float4 v0 = embv[(size_t)t0 * 64 + lane];
      float4 v1 = embv[(size_t)t1 * 64 + lane];
      float4 v2 = embv[(size_t)t2 * 64 + lane];
      float4 v3 = embv[(size_t)t3 * 64 + lane];
      a0.x += v0.x; a0.y += v0.y; a0.z += v0.z; a0.w += v0.w;
      a1.x += v1.x; a1.y += v1.y; a1.z += v1.z; a1.w += v1.w;
      a2.x += v2.x; a2.y += v2.y; a2.z += v2.z; a2.w += v2.w;
      a3.x += v3.x; a3.y += v3.y; a3.z += v3.z; a3.w += v3.w;
    }
    for (; j < nt; j++) {
      int t0 = __shfl(tk, j);
      float4 v0 = embv[(size_t)t0 * 64 + lane];
      a0.x += v0.x; a0.y += v0.y; a0.z += v0.z; a0.w += v0.w;
    }
  }
  float4 r;
  r.x = (a0.x + a1.x) + (a2.x + a3.x);
  r.y = (a0.y + a1.y) + (a2.y + a3.y);
  r.z = (a0.z + a1.z) + (a2.z + a3.z);
  r.w = (a0.w + a1.w) + (a2.w + a3.w);
  __shared__ float4 part[2][64];
  if (half) part[wv >> 1][lane] = r;
  __syncthreads();
  if (!half) {
    float4 o = part[wv >> 1][lane];
    const float inv = 1.0f / (float)len;
    r.x = (r.x + o.x) * inv;
    r.y = (r.y + o.y) * inv;
    r.z = (r.z + o.z) * inv;
    r.w = (r.w + o.w) * inv;
    ((float4*)pooled)[(size_t)row * 64 + lane] = r;
  }
}

// ============================================================================
// K2: z = pooled @ W1^T + b1 + per-block BN partials (verified round-0
// structure), with BN FINALIZE fused via last-block-done: the 256th block to
// finish reduces psum/psq (256x256 each, coalesced) -> A[d], C[d].
// ============================================================================
__global__ __launch_bounds__(256) void gemm_stats_bn_kernel(
    const float* __restrict__ pooled, const float* __restrict__ W1p,
    const float* __restrict__ b1, float* __restrict__ z,
    float* __restrict__ psum, float* __restrict__ psq,
    const float* __restrict__ gamma, const float* __restrict__ beta,
    float* __restrict__ A, float* __restrict__ C, int* __restrict__ cnts) {
  __shared__ float4 SH[1024];   // 16 KB: pooled tile during loop, stats after
  const int tid = threadIdx.x;
  const int b0 = blockIdx.x * 16;
  const float4* pooled4 = (const float4*)pooled;
#pragma unroll
  for (int i = 0; i < 4; i++)
    SH[tid + i * 256] = pooled4[(size_t)b0 * 64 + tid + i * 256];
  __syncthreads();
  const int wv = tid >> 6, lane = tid & 63;
  const int r0 = wv * 4;
  float4 bb = ((const float4*)b1)[lane];
  float acc[4][4];
#pragma unroll
  for (int r = 0; r < 4; r++) {
    acc[r][0] = bb.x; acc[r][1] = bb.y; acc[r][2] = bb.z; acc[r][3] = bb.w;
  }
  const float4* w4 = (const float4*)W1p;
  for (int kb = 0; kb < 64; kb++) {
    float4 wk0 = w4[kb * 256 + lane * 4 + 0];
    float4 wk1 = w4[kb * 256 + lane * 4 + 1];
    float4 wk2 = w4[kb * 256 + lane * 4 + 2];
    float4 wk3 = w4[kb * 256 + lane * 4 + 3];
#pragma unroll
    for (int r = 0; r < 4; r++) {
      float4 p = SH[(r0 + r) * 64 + kb];   // wave-uniform -> LDS broadcast
      acc[r][0] += p.x * wk0.x + p.y * wk0.y + p.z * wk0.z + p.w * wk0.w;
      acc[r][1] += p.x * wk1.x + p.y * wk1.y + p.z * wk1.z + p.w * wk1.w;
      acc[r][2] += p.x * wk2.x + p.y * wk2.y + p.z * wk2.z + p.w * wk2.w;
      acc[r][3] += p.x * wk3.x + p.y * wk3.y + p.z * wk3.z + p.w * wk3.w;
    }
  }
  float4* z4 = (float4*)z;
  float4 s = make_float4(0.f, 0.f, 0.f, 0.f), q = s;
#pragma unroll
  for (int r = 0; r < 4; r++) {
    float4 o = make_float4(acc[r][0], acc[r][1], acc[r][2], acc[r][3]);
    z4[(size_t)(b0 + r0 + r) * 64 + lane] = o;
    s.x += o.x; s.y += o.y; s.z += o.z; s.w += o.w;
    q.x += o.x * o.x; q.y += o.y * o.y; q.z += o.z * o.z; q.w += o.w * o.w;
  }
  __syncthreads();   // done reading pooled tile; reuse SH for stats
  SH[wv * 64 + lane] = s;
  SH[256 + wv * 64 + lane] = q;
  __syncthreads();
  if (tid < 64) {
    float4 S = make_float4(0.f, 0.f, 0.f, 0.f), Q = S;
#pragma unroll
    for (int w = 0; w < 4; w++) {
      float4 a = SH[w * 64 + tid];
      float4 b = SH[256 + w * 64 + tid];
      S.x += a.x; S.y += a.y; S.z += a.z; S.w += a.w;
      Q.x += b.x; Q.y += b.y; Q.z += b.z; Q.w += b.w;
    }
    ((float4*)psum)[blockIdx.x * 64 + tid] = S;
    ((float4*)psq)[blockIdx.x * 64 + tid] = Q;
  }
  // ---- last-block BN finalize ----
  __shared__ int isLast;
  __threadfence();   // make psum/psq visible device-wide (release)
  if (tid == 0) isLast = (atomicAdd(&cnts[0], 1) == 255);
  __syncthreads();
  if (isLast) {
    __threadfence();   // acquire: see all blocks' psum/psq
    float S = 0.f, Q = 0.f;
    for (int b = 0; b < 256; b++) {    // coalesced across tid
      S += psum[b * 256 + tid];
      Q += psq[b * 256 + tid];
    }
    float m = S * (1.0f / 4096.0f);
    float v = Q * (1.0f / 4096.0f) - m * m;
    float a = gamma[tid] * rsqrtf(v + 1e-5f);
    A[tid] = a;
    C[tid] = beta[tid] - m * a;
  }
}

// ============================================================================
// K3: BN-apply + ReLU + dot head + per-row BCE (verified), with LOSS fused via
// last-block-done: blocks write a per-block BCE partial (deterministic tree);
// the 1024th block reduces bpart[1024] -> out[0].
// ============================================================================
__global__ __launch_bounds__(256) void head_loss_kernel(
    const float* __restrict__ z, const float* __restrict__ A,
    const float* __restrict__ C, const float* __restrict__ w2,
    const float* __restrict__ b2, const float* __restrict__ t,
    float* __restrict__ out, float* __restrict__ bpart, int* __restrict__ cnts) {
  const int tid = threadIdx.x;
  const int wv = tid >> 6, lane = tid & 63;
  const int b = blockIdx.x * 4 + wv;
  float4 A4 = ((const float4*)A)[lane];
  float4 C4 = ((const float4*)C)[lane];
  float4 w24 = ((const float4*)w2)[lane];
  float4 zv = ((const float4*)z)[(size_t)b * 64 + lane];
  float h0 = fmaxf(A4.x * zv.x + C4.x, 0.f);
  float h1 = fmaxf(A4.y * zv.y + C4.y, 0.f);
  float h2 = fmaxf(A4.z * zv.z + C4.z, 0.f);
  float h3 = fmaxf(A4.w * zv.w + C4.w, 0.f);
  float part = h0 * w24.x + h1 * w24.y + h2 * w24.z + h3 * w24.w;
#pragma unroll
  for (int off = 32; off > 0; off >>= 1) part += __shfl_down(part, off);
  __shared__ float red[4];
  if (lane == 0) {
    float logit = part + b2[0];
    out[1 + b] = logit;
    float tb = t[b];
    red[wv] = fmaxf(logit, 0.f) - logit * tb + log1pf(expf(-fabsf(logit)));
  }
  __syncthreads();
  if (tid == 0)
    bpart[blockIdx.x] = (red[0] + red[1]) + (red[2] + red[3]);
  // ---- last-block loss finalize (deterministic fixed-tree reduction) ----
  __shared__ int isLast;
  __threadfence();
  if (tid == 0) isLast = (atomicAdd(&cnts[1], 1) == 1023);
  __syncthreads();
  if (isLast) {
    __threadfence();
    float s = 0.f;
#pragma unroll
    for (int i = 0; i < 4; i++) s += bpart[tid + i * 256];
#pragma unroll
    for (int off = 32; off > 0; off >>= 1) s += __shfl_down(s, off);
    __shared__ float fin[4];
    if (lane == 0) fin[wv] = s;
    __syncthreads();
    if (tid == 0)
      out[0] = ((fin[0] + fin[1]) + (fin[2] + fin[3])) * (1.0f / 4096.0f);
  }
}

extern "C" void kernel_launch(void* const* d_in, const int* in_sizes, int n_in,
                              void* d_out, int out_size, void* d_ws, size_t ws_size,
                              hipStream_t stream) {
  const int* tokens = (const int*)d_in[0];
  const int* lengths = (const int*)d_in[1];
  const float* t = (const float*)d_in[2];
  const float* emb = (const float*)d_in[3];
  const float* W1 = (const float*)d_in[4];
  const float* b1 = (const float*)d_in[5];
  const float* gamma = (const float*)d_in[6];
  const float* beta = (const float*)d_in[7];
  const float* w2 = (const float*)d_in[8];
  const float* b2 = (const float*)d_in[9];
  float* out = (float*)d_out;

  float* wsf = (float*)d_ws;
  float* pooled = wsf;                 // 1,048,576 floats
  float* z = wsf + 1048576;            // 1,048,576
  float* W1p = wsf + 2097152;          // 65,536
  float* psum = wsf + 2162688;         // 65,536 (256 blocks x 256 dims)
  float* psq = wsf + 2228224;          // 65,536
  float* A = wsf + 2293760;            // 256
  float* C = wsf + 2294016;            // 256
  float* bpart = wsf + 2294272;        // 1,024
  int* cnts = (int*)(wsf + 2295296);   // 8 ints (zeroed by K1 block 0)
  // total ~8.78 MiB of d_ws

  pool_pack_kernel<<<2048, 256, 0, stream>>>(tokens, lengths, emb, pooled,
                                             W1, W1p, cnts);
  gemm_stats_bn_kernel<<<256, 256, 0, stream>>>(pooled, W1p, b1, z, psum, psq,
                                                gamma, beta, A, C, cnts);
  head_loss_kernel<<<1024, 256, 0, stream>>>(z, A, C, w2, b2, t, out, bpart, cnts);
}

// Round 5
// 236.916 us; speedup vs baseline: 1.4382x; 1.4382x over previous
//
#include <hip/hip_runtime.h>
#include <math.h>

#define L_ 200

// ============================================================================
// K1: pooling, 2 waves per row with MOD-2 INTERLEAVED token split (balanced:
// each wave does ceil/floor(len/2) gathers regardless of len -> shorter
// critical path than the alternating-64-block split), 4-deep gather ILP.
// Blocks 0..63 also transpose-pack W1 (one float4 per thread).
// ============================================================================
__global__ __launch_bounds__(256) void pool_pack_kernel(
    const int* __restrict__ tokens, const int* __restrict__ lengths,
    const float* __restrict__ emb, float* __restrict__ pooled,
    const float* __restrict__ W1, float* __restrict__ W1p) {
  const int tid = threadIdx.x;
  if (blockIdx.x < 64) {
    float4 v = ((const float4*)W1)[tid * 64 + blockIdx.x];
    ((float4*)W1p)[blockIdx.x * 256 + tid] = v;
  }
  const int wv = tid >> 6, lane = tid & 63;
  const int row = blockIdx.x * 2 + (wv >> 1);
  const int half = wv & 1;
  const int len = lengths[row];
  const int cnt = (len + 1 - half) >> 1;   // tokens with index%2 == half
  const int* trow = tokens + row * L_;
  const float4* embv = (const float4*)emb;   // emb row = 64 float4
  float4 a0 = make_float4(0.f, 0.f, 0.f, 0.f);
  float4 a1 = a0, a2 = a0, a3 = a0;
  for (int b0 = 0; b0 < cnt; b0 += 64) {
    int nt = cnt - b0; nt = nt > 64 ? 64 : nt;
    int tk = (lane < nt) ? trow[half + 2 * (b0 + lane)] : 0;  // stride-2 load
    int j = 0;
    for (; j + 4 <= nt; j += 4) {
      int t0 = __shfl(tk, j);
      int t1 = __shfl(tk, j + 1);
      int t2 = __shfl(tk, j + 2);
      int t3 = __shfl(tk, j + 3);
      float4 v0 = embv[(size_t)t0 * 64 + lane];
      float4 v1 = embv[(size_t)t1 * 64 + lane];
      float4 v2 = embv[(size_t)t2 * 64 + lane];
      float4 v3 = embv[(size_t)t3 * 64 + lane];
      a0.x += v0.x; a0.y += v0.y; a0.z += v0.z; a0.w += v0.w;
      a1.x += v1.x; a1.y += v1.y; a1.z += v1.z; a1.w += v1.w;
      a2.x += v2.x; a2.y += v2.y; a2.z += v2.z; a2.w += v2.w;
      a3.x += v3.x; a3.y += v3.y; a3.z += v3.z; a3.w += v3.w;
    }
    for (; j < nt; j++) {
      int t0 = __shfl(tk, j);
      float4 v0 = embv[(size_t)t0 * 64 + lane];
      a0.x += v0.x; a0.y += v0.y; a0.z += v0.z; a0.w += v0.w;
    }
  }
  float4 r;
  r.x = (a0.x + a1.x) + (a2.x + a3.x);
  r.y = (a0.y + a1.y) + (a2.y + a3.y);
  r.z = (a0.z + a1.z) + (a2.z + a3.z);
  r.w = (a0.w + a1.w) + (a2.w + a3.w);
  __shared__ float4 part[2][64];
  if (half) part[wv >> 1][lane] = r;
  __syncthreads();
  if (!half) {
    float4 o = part[wv >> 1][lane];
    const float inv = 1.0f / (float)len;
    r.x = (r.x + o.x) * inv;
    r.y = (r.y + o.y) * inv;
    r.z = (r.z + o.z) * inv;
    r.w = (r.w + o.w) * inv;
    ((float4*)pooled)[(size_t)row * 64 + lane] = r;
  }
}

// ---------------- K2: z = pooled @ W1^T + b1, fused per-block BN partials ------
__global__ __launch_bounds__(256) void gemm_stats_kernel(
    const float* __restrict__ pooled, const float* __restrict__ W1p,
    const float* __restrict__ b1, float* __restrict__ z,
    float* __restrict__ psum, float* __restrict__ psq) {
  __shared__ float4 SH[1024];   // 16 KB: pooled tile during loop, stats after
  const int tid = threadIdx.x;
  const int b0 = blockIdx.x * 16;
  const float4* pooled4 = (const float4*)pooled;
#pragma unroll
  for (int i = 0; i < 4; i++)
    SH[tid + i * 256] = pooled4[(size_t)b0 * 64 + tid + i * 256];
  __syncthreads();
  const int wv = tid >> 6, lane = tid & 63;
  const int r0 = wv * 4;
  float4 bb = ((const float4*)b1)[lane];
  float acc[4][4];
#pragma unroll
  for (int r = 0; r < 4; r++) {
    acc[r][0] = bb.x; acc[r][1] = bb.y; acc[r][2] = bb.z; acc[r][3] = bb.w;
  }
  const float4* w4 = (const float4*)W1p;
  for (int kb = 0; kb < 64; kb++) {
    float4 wk0 = w4[kb * 256 + lane * 4 + 0];
    float4 wk1 = w4[kb * 256 + lane * 4 + 1];
    float4 wk2 = w4[kb * 256 + lane * 4 + 2];
    float4 wk3 = w4[kb * 256 + lane * 4 + 3];
#pragma unroll
    for (int r = 0; r < 4; r++) {
      float4 p = SH[(r0 + r) * 64 + kb];   // wave-uniform -> LDS broadcast
      acc[r][0] += p.x * wk0.x + p.y * wk0.y + p.z * wk0.z + p.w * wk0.w;
      acc[r][1] += p.x * wk1.x + p.y * wk1.y + p.z * wk1.z + p.w * wk1.w;
      acc[r][2] += p.x * wk2.x + p.y * wk2.y + p.z * wk2.z + p.w * wk2.w;
      acc[r][3] += p.x * wk3.x + p.y * wk3.y + p.z * wk3.z + p.w * wk3.w;
    }
  }
  float4* z4 = (float4*)z;
  float4 s = make_float4(0.f, 0.f, 0.f, 0.f), q = s;
#pragma unroll
  for (int r = 0; r < 4; r++) {
    float4 o = make_float4(acc[r][0], acc[r][1], acc[r][2], acc[r][3]);
    z4[(size_t)(b0 + r0 + r) * 64 + lane] = o;
    s.x += o.x; s.y += o.y; s.z += o.z; s.w += o.w;
    q.x += o.x * o.x; q.y += o.y * o.y; q.z += o.z * o.z; q.w += o.w * o.w;
  }
  __syncthreads();   // done reading pooled tile; reuse SH for stats
  SH[wv * 64 + lane] = s;
  SH[256 + wv * 64 + lane] = q;
  __syncthreads();
  if (tid < 64) {
    float4 S = make_float4(0.f, 0.f, 0.f, 0.f), Q = S;
#pragma unroll
    for (int w = 0; w < 4; w++) {
      float4 a = SH[w * 64 + tid];
      float4 b = SH[256 + w * 64 + tid];
      S.x += a.x; S.y += a.y; S.z += a.z; S.w += a.w;
      Q.x += b.x; Q.y += b.y; Q.z += b.z; Q.w += b.w;
    }
    ((float4*)psum)[blockIdx.x * 64 + tid] = S;
    ((float4*)psq)[blockIdx.x * 64 + tid] = Q;
  }
}

// ---------------- K3: finalize BN: A[d] = gamma*rsqrt(var+eps), C[d] = beta-mu*A
__global__ __launch_bounds__(256) void bn_reduce_kernel(
    const float* __restrict__ psum, const float* __restrict__ psq,
    const float* __restrict__ gamma, const float* __restrict__ beta,
    float* __restrict__ A, float* __restrict__ C) {
  const int t = threadIdx.x;
  const int dd = t & 15, c = t >> 4;
  const int d = blockIdx.x * 16 + dd;
  float s = 0.f, q = 0.f;
#pragma unroll
  for (int i = 0; i < 16; i++) {
    int p = c * 16 + i;
    s += psum[p * 256 + d];
    q += psq[p * 256 + d];
  }
  __shared__ float sl[16][17], ql[16][17];
  sl[c][dd] = s; ql[c][dd] = q;
  __syncthreads();
  if (t < 16) {
    float S = 0.f, Q = 0.f;
#pragma unroll
    for (int c2 = 0; c2 < 16; c2++) { S += sl[c2][t]; Q += ql[c2][t]; }
    int dg = blockIdx.x * 16 + t;
    float m = S * (1.0f / 4096.0f);
    float v = Q * (1.0f / 4096.0f) - m * m;
    float a = gamma[dg] * rsqrtf(v + 1e-5f);
    A[dg] = a;
    C[dg] = beta[dg] - m * a;
  }
}

// ---------------- K4: BN-apply + ReLU + dot head + per-row BCE; wave per row ---
__global__ __launch_bounds__(256) void head_kernel(
    const float* __restrict__ z, const float* __restrict__ A,
    const float* __restrict__ C, const float* __restrict__ w2,
    const float* __restrict__ b2, const float* __restrict__ t,
    float* __restrict__ out, float* __restrict__ bce) {
  const int tid = threadIdx.x;
  const int wv = tid >> 6, lane = tid & 63;
  const int b = blockIdx.x * 4 + wv;
  float4 A4 = ((const float4*)A)[lane];
  float4 C4 = ((const float4*)C)[lane];
  float4 w24 = ((const float4*)w2)[lane];
  float4 zv = ((const float4*)z)[(size_t)b * 64 + lane];
  float h0 = fmaxf(A4.x * zv.x + C4.x, 0.f);
  float h1 = fmaxf(A4.y * zv.y + C4.y, 0.f);
  float h2 = fmaxf(A4.z * zv.z + C4.z, 0.f);
  float h3 = fmaxf(A4.w * zv.w + C4.w, 0.f);
  float part = h0 * w24.x + h1 * w24.y + h2 * w24.z + h3 * w24.w;
#pragma unroll
  for (int off = 32; off > 0; off >>= 1) part += __shfl_down(part, off);
  if (lane == 0) {
    float logit = part + b2[0];
    out[1 + b] = logit;
    float tb = t[b];
    bce[b] = fmaxf(logit, 0.f) - logit * tb + log1pf(expf(-fabsf(logit)));
  }
}

// ---------------- K5: final deterministic loss reduction ----------------------
__global__ __launch_bounds__(256) void loss_kernel(const float* __restrict__ bce,
                                                   float* __restrict__ out) {
  __shared__ float red[4];
  const int tid = threadIdx.x;
  float s = 0.f;
  for (int i = 0; i < 16; i++) s += bce[tid + i * 256];
#pragma unroll
  for (int off = 32; off > 0; off >>= 1) s += __shfl_down(s, off);
  if ((tid & 63) == 0) red[tid >> 6] = s;
  __syncthreads();
  if (tid == 0) out[0] = (red[0] + red[1] + red[2] + red[3]) * (1.0f / 4096.0f);
}

extern "C" void kernel_launch(void* const* d_in, const int* in_sizes, int n_in,
                              void* d_out, int out_size, void* d_ws, size_t ws_size,
                              hipStream_t stream) {
  const int* tokens = (const int*)d_in[0];
  const int* lengths = (const int*)d_in[1];
  const float* t = (const float*)d_in[2];
  const float* emb = (const float*)d_in[3];
  const float* W1 = (const float*)d_in[4];
  const float* b1 = (const float*)d_in[5];
  const float* gamma = (const float*)d_in[6];
  const float* beta = (const float*)d_in[7];
  const float* w2 = (const float*)d_in[8];
  const float* b2 = (const float*)d_in[9];
  float* out = (float*)d_out;

  float* wsf = (float*)d_ws;
  float* pooled = wsf;                 // 1,048,576 floats
  float* z = wsf + 1048576;            // 1,048,576
  float* W1p = wsf + 2097152;          // 65,536
  float* psum = wsf + 2162688;         // 65,536 (256 blocks x 256 dims)
  float* psq = wsf + 2228224;          // 65,536
  float* A = wsf + 2293760;            // 256
  float* C = wsf + 2294016;            // 256
  float* bce = wsf + 2294272;          // 4,096
  // total ~8.8 MiB of d_ws

  pool_pack_kernel<<<2048, 256, 0, stream>>>(tokens, lengths, emb, pooled, W1, W1p);
  gemm_stats_kernel<<<256, 256, 0, stream>>>(pooled, W1p, b1, z, psum, psq);
  bn_reduce_kernel<<<16, 256, 0, stream>>>(psum, psq, gamma, beta, A, C);
  head_kernel<<<1024, 256, 0, stream>>>(z, A, C, w2, b2, t, out, bce);
  loss_kernel<<<1, 256, 0, stream>>>(bce, out);
}

// Round 6
// 235.581 us; speedup vs baseline: 1.4463x; 1.0057x over previous
//
#include <hip/hip_runtime.h>
#include <math.h>

#define L_ 200

// ============================================================================
// K1: pooling, ONE row per block, 4 waves with MOD-4 interleaved token split
// (each wave gathers tokens with index%4==wv, <=50 gathers -> single loop
// trip), 4-deep gather ILP, 4-way LDS merge. Grid = 4096 blocks = 2x the
// resident capacity (8 blocks/CU x 256 CUs) so the hardware dispatch queue
// refills CU slots as short blocks retire -> flat occupancy (round-5 showed
// 64% time-avg occupancy from tail decay at exactly-resident grid).
// Blocks 0..63 also transpose-pack W1 (one float4 per thread).
// ============================================================================
__global__ __launch_bounds__(256) void pool_pack_kernel(
    const int* __restrict__ tokens, const int* __restrict__ lengths,
    const float* __restrict__ emb, float* __restrict__ pooled,
    const float* __restrict__ W1, float* __restrict__ W1p) {
  const int tid = threadIdx.x;
  if (blockIdx.x < 64) {
    float4 v = ((const float4*)W1)[tid * 64 + blockIdx.x];
    ((float4*)W1p)[blockIdx.x * 256 + tid] = v;
  }
  const int wv = tid >> 6, lane = tid & 63;
  const int row = blockIdx.x;
  const int len = lengths[row];
  const int cnt = (len + 3 - wv) >> 2;   // tokens with index%4 == wv
  const int* trow = tokens + row * L_;
  const float4* embv = (const float4*)emb;   // emb row = 64 float4
  float4 a0 = make_float4(0.f, 0.f, 0.f, 0.f);
  float4 a1 = a0, a2 = a0, a3 = a0;
  for (int b0 = 0; b0 < cnt; b0 += 64) {     // cnt <= 50: single trip
    int nt = cnt - b0; nt = nt > 64 ? 64 : nt;
    int tk = (lane < nt) ? trow[wv + 4 * (b0 + lane)] : 0;  // stride-4 load
    int j = 0;
    for (; j + 4 <= nt; j += 4) {
      int t0 = __shfl(tk, j);
      int t1 = __shfl(tk, j + 1);
      int t2 = __shfl(tk, j + 2);
      int t3 = __shfl(tk, j + 3);
      float4 v0 = embv[(size_t)t0 * 64 + lane];
      float4 v1 = embv[(size_t)t1 * 64 + lane];
      float4 v2 = embv[(size_t)t2 * 64 + lane];
      float4 v3 = embv[(size_t)t3 * 64 + lane];
      a0.x += v0.x; a0.y += v0.y; a0.z += v0.z; a0.w += v0.w;
      a1.x += v1.x; a1.y += v1.y; a1.z += v1.z; a1.w += v1.w;
      a2.x += v2.x; a2.y += v2.y; a2.z += v2.z; a2.w += v2.w;
      a3.x += v3.x; a3.y += v3.y; a3.z += v3.z; a3.w += v3.w;
    }
    for (; j < nt; j++) {
      int t0 = __shfl(tk, j);
      float4 v0 = embv[(size_t)t0 * 64 + lane];
      a0.x += v0.x; a0.y += v0.y; a0.z += v0.z; a0.w += v0.w;
    }
  }
  float4 r;
  r.x = (a0.x + a1.x) + (a2.x + a3.x);
  r.y = (a0.y + a1.y) + (a2.y + a3.y);
  r.z = (a0.z + a1.z) + (a2.z + a3.z);
  r.w = (a0.w + a1.w) + (a2.w + a3.w);
  __shared__ float4 part[4][64];
  part[wv][lane] = r;
  __syncthreads();
  if (wv == 0) {
    float4 p1 = part[1][lane], p2 = part[2][lane], p3 = part[3][lane];
    const float inv = 1.0f / (float)len;
    r.x = ((r.x + p1.x) + (p2.x + p3.x)) * inv;
    r.y = ((r.y + p1.y) + (p2.y + p3.y)) * inv;
    r.z = ((r.z + p1.z) + (p2.z + p3.z)) * inv;
    r.w = ((r.w + p1.w) + (p2.w + p3.w)) * inv;
    ((float4*)pooled)[(size_t)row * 64 + lane] = r;
  }
}

// ---------------- K2: z = pooled @ W1^T + b1, fused per-block BN partials ------
__global__ __launch_bounds__(256) void gemm_stats_kernel(
    const float* __restrict__ pooled, const float* __restrict__ W1p,
    const float* __restrict__ b1, float* __restrict__ z,
    float* __restrict__ psum, float* __restrict__ psq) {
  __shared__ float4 SH[1024];   // 16 KB: pooled tile during loop, stats after
  const int tid = threadIdx.x;
  const int b0 = blockIdx.x * 16;
  const float4* pooled4 = (const float4*)pooled;
#pragma unroll
  for (int i = 0; i < 4; i++)
    SH[tid + i * 256] = pooled4[(size_t)b0 * 64 + tid + i * 256];
  __syncthreads();
  const int wv = tid >> 6, lane = tid & 63;
  const int r0 = wv * 4;
  float4 bb = ((const float4*)b1)[lane];
  float acc[4][4];
#pragma unroll
  for (int r = 0; r < 4; r++) {
    acc[r][0] = bb.x; acc[r][1] = bb.y; acc[r][2] = bb.z; acc[r][3] = bb.w;
  }
  const float4* w4 = (const float4*)W1p;
  for (int kb = 0; kb < 64; kb++) {
    float4 wk0 = w4[kb * 256 + lane * 4 + 0];
    float4 wk1 = w4[kb * 256 + lane * 4 + 1];
    float4 wk2 = w4[kb * 256 + lane * 4 + 2];
    float4 wk3 = w4[kb * 256 + lane * 4 + 3];
#pragma unroll
    for (int r = 0; r < 4; r++) {
      float4 p = SH[(r0 + r) * 64 + kb];   // wave-uniform -> LDS broadcast
      acc[r][0] += p.x * wk0.x + p.y * wk0.y + p.z * wk0.z + p.w * wk0.w;
      acc[r][1] += p.x * wk1.x + p.y * wk1.y + p.z * wk1.z + p.w * wk1.w;
      acc[r][2] += p.x * wk2.x + p.y * wk2.y + p.z * wk2.z + p.w * wk2.w;
      acc[r][3] += p.x * wk3.x + p.y * wk3.y + p.z * wk3.z + p.w * wk3.w;
    }
  }
  float4* z4 = (float4*)z;
  float4 s = make_float4(0.f, 0.f, 0.f, 0.f), q = s;
#pragma unroll
  for (int r = 0; r < 4; r++) {
    float4 o = make_float4(acc[r][0], acc[r][1], acc[r][2], acc[r][3]);
    z4[(size_t)(b0 + r0 + r) * 64 + lane] = o;
    s.x += o.x; s.y += o.y; s.z += o.z; s.w += o.w;
    q.x += o.x * o.x; q.y += o.y * o.y; q.z += o.z * o.z; q.w += o.w * o.w;
  }
  __syncthreads();   // done reading pooled tile; reuse SH for stats
  SH[wv * 64 + lane] = s;
  SH[256 + wv * 64 + lane] = q;
  __syncthreads();
  if (tid < 64) {
    float4 S = make_float4(0.f, 0.f, 0.f, 0.f), Q = S;
#pragma unroll
    for (int w = 0; w < 4; w++) {
      float4 a = SH[w * 64 + tid];
      float4 b = SH[256 + w * 64 + tid];
      S.x += a.x; S.y += a.y; S.z += a.z; S.w += a.w;
      Q.x += b.x; Q.y += b.y; Q.z += b.z; Q.w += b.w;
    }
    ((float4*)psum)[blockIdx.x * 64 + tid] = S;
    ((float4*)psq)[blockIdx.x * 64 + tid] = Q;
  }
}

// ---------------- K3: finalize BN: A[d] = gamma*rsqrt(var+eps), C[d] = beta-mu*A
__global__ __launch_bounds__(256) void bn_reduce_kernel(
    const float* __restrict__ psum, const float* __restrict__ psq,
    const float* __restrict__ gamma, const float* __restrict__ beta,
    float* __restrict__ A, float* __restrict__ C) {
  const int t = threadIdx.x;
  const int dd = t & 15, c = t >> 4;
  const int d = blockIdx.x * 16 + dd;
  float s = 0.f, q = 0.f;
#pragma unroll
  for (int i = 0; i < 16; i++) {
    int p = c * 16 + i;
    s += psum[p * 256 + d];
    q += psq[p * 256 + d];
  }
  __shared__ float sl[16][17], ql[16][17];
  sl[c][dd] = s; ql[c][dd] = q;
  __syncthreads();
  if (t < 16) {
    float S = 0.f, Q = 0.f;
#pragma unroll
    for (int c2 = 0; c2 < 16; c2++) { S += sl[c2][t]; Q += ql[c2][t]; }
    int dg = blockIdx.x * 16 + t;
    float m = S * (1.0f / 4096.0f);
    float v = Q * (1.0f / 4096.0f) - m * m;
    float a = gamma[dg] * rsqrtf(v + 1e-5f);
    A[dg] = a;
    C[dg] = beta[dg] - m * a;
  }
}

// ---------------- K4: BN-apply + ReLU + dot head + per-row BCE; wave per row ---
__global__ __launch_bounds__(256) void head_kernel(
    const float* __restrict__ z, const float* __restrict__ A,
    const float* __restrict__ C, const float* __restrict__ w2,
    const float* __restrict__ b2, const float* __restrict__ t,
    float* __restrict__ out, float* __restrict__ bce) {
  const int tid = threadIdx.x;
  const int wv = tid >> 6, lane = tid & 63;
  const int b = blockIdx.x * 4 + wv;
  float4 A4 = ((const float4*)A)[lane];
  float4 C4 = ((const float4*)C)[lane];
  float4 w24 = ((const float4*)w2)[lane];
  float4 zv = ((const float4*)z)[(size_t)b * 64 + lane];
  float h0 = fmaxf(A4.x * zv.x + C4.x, 0.f);
  float h1 = fmaxf(A4.y * zv.y + C4.y, 0.f);
  float h2 = fmaxf(A4.z * zv.z + C4.z, 0.f);
  float h3 = fmaxf(A4.w * zv.w + C4.w, 0.f);
  float part = h0 * w24.x + h1 * w24.y + h2 * w24.z + h3 * w24.w;
#pragma unroll
  for (int off = 32; off > 0; off >>= 1) part += __shfl_down(part, off);
  if (lane == 0) {
    float logit = part + b2[0];
    out[1 + b] = logit;
    float tb = t[b];
    bce[b] = fmaxf(logit, 0.f) - logit * tb + log1pf(expf(-fabsf(logit)));
  }
}

// ---------------- K5: final deterministic loss reduction ----------------------
__global__ __launch_bounds__(256) void loss_kernel(const float* __restrict__ bce,
                                                   float* __restrict__ out) {
  __shared__ float red[4];
  const int tid = threadIdx.x;
  float s = 0.f;
  for (int i = 0; i < 16; i++) s += bce[tid + i * 256];
#pragma unroll
  for (int off = 32; off > 0; off >>= 1) s += __shfl_down(s, off);
  if ((tid & 63) == 0) red[tid >> 6] = s;
  __syncthreads();
  if (tid == 0) out[0] = (red[0] + red[1] + red[2] + red[3]) * (1.0f / 4096.0f);
}

extern "C" void kernel_launch(void* const* d_in, const int* in_sizes, int n_in,
                              void* d_out, int out_size, void* d_ws, size_t ws_size,
                              hipStream_t stream) {
  const int* tokens = (const int*)d_in[0];
  const int* lengths = (const int*)d_in[1];
  const float* t = (const float*)d_in[2];
  const float* emb = (const float*)d_in[3];
  const float* W1 = (const float*)d_in[4];
  const float* b1 = (const float*)d_in[5];
  const float* gamma = (const float*)d_in[6];
  const float* beta = (const float*)d_in[7];
  const float* w2 = (const float*)d_in[8];
  const float* b2 = (const float*)d_in[9];
  float* out = (float*)d_out;

  float* wsf = (float*)d_ws;
  float* pooled = wsf;                 // 1,048,576 floats
  float* z = wsf + 1048576;            // 1,048,576
  float* W1p = wsf + 2097152;          // 65,536
  float* psum = wsf + 2162688;         // 65,536 (256 blocks x 256 dims)
  float* psq = wsf + 2228224;          // 65,536
  float* A = wsf + 2293760;            // 256
  float* C = wsf + 2294016;            // 256
  float* bce = wsf + 2294272;          // 4,096
  // total ~8.8 MiB of d_ws

  pool_pack_kernel<<<4096, 256, 0, stream>>>(tokens, lengths, emb, pooled, W1, W1p);
  gemm_stats_kernel<<<256, 256, 0, stream>>>(pooled, W1p, b1, z, psum, psq);
  bn_reduce_kernel<<<16, 256, 0, stream>>>(psum, psq, gamma, beta, A, C);
  head_kernel<<<1024, 256, 0, stream>>>(z, A, C, w2, b2, t, out, bce);
  loss_kernel<<<1, 256, 0, stream>>>(bce, out);
}

// Round 8
// 234.847 us; speedup vs baseline: 1.4509x; 1.0031x over previous
//
#include <hip/hip_runtime.h>
#include <math.h>

#define L_ 200

// ============================================================================
// K1: pooling, ONE row per block, 4 waves with MOD-4 interleaved token split
// (each wave gathers tokens with index%4==wv, <=50 gathers -> single loop
// trip), 8-DEEP gather ILP (in-flight bytes ~42 MB device-wide; rounds 1/6
// established delivered BW scales linearly with in-flight at constant ~3.8us
// effective latency), 4-way LDS merge. Grid = 4096 blocks (oversubscribed).
// Blocks 0..63 also transpose-pack W1 (one float4 per thread).
// ============================================================================
__global__ __launch_bounds__(256) void pool_pack_kernel(
    const int* __restrict__ tokens, const int* __restrict__ lengths,
    const float* __restrict__ emb, float* __restrict__ pooled,
    const float* __restrict__ W1, float* __restrict__ W1p) {
  const int tid = threadIdx.x;
  if (blockIdx.x < 64) {
    float4 v = ((const float4*)W1)[tid * 64 + blockIdx.x];
    ((float4*)W1p)[blockIdx.x * 256 + tid] = v;
  }
  const int wv = tid >> 6, lane = tid & 63;
  const int row = blockIdx.x;
  const int len = lengths[row];
  const int cnt = (len + 3 - wv) >> 2;   // tokens with index%4 == wv
  const int* trow = tokens + row * L_;
  const float4* embv = (const float4*)emb;   // emb row = 64 float4
  float4 a0 = make_float4(0.f, 0.f, 0.f, 0.f);
  float4 a1 = a0, a2 = a0, a3 = a0, a4 = a0, a5 = a0, a6 = a0, a7 = a0;
  for (int b0 = 0; b0 < cnt; b0 += 64) {     // cnt <= 50: single trip
    int nt = cnt - b0; nt = nt > 64 ? 64 : nt;
    int tk = (lane < nt) ? trow[wv + 4 * (b0 + lane)] : 0;  // stride-4 load
    int j = 0;
    for (; j + 8 <= nt; j += 8) {            // 8 gathers in flight
      int t0 = __shfl(tk, j);
      int t1 = __shfl(tk, j + 1);
      int t2 = __shfl(tk, j + 2);
      int t3 = __shfl(tk, j + 3);
      int t4 = __shfl(tk, j + 4);
      int t5 = __shfl(tk, j + 5);
      int t6 = __shfl(tk, j + 6);
      int t7 = __shfl(tk, j + 7);
      float4 v0 = embv[(size_t)t0 * 64 + lane];
      float4 v1 = embv[(size_t)t1 * 64 + lane];
      float4 v2 = embv[(size_t)t2 * 64 + lane];
      float4 v3 = embv[(size_t)t3 * 64 + lane];
      float4 v4 = embv[(size_t)t4 * 64 + lane];
      float4 v5 = embv[(size_t)t5 * 64 + lane];
      float4 v6 = embv[(size_t)t6 * 64 + lane];
      float4 v7 = embv[(size_t)t7 * 64 + lane];
      a0.x += v0.x; a0.y += v0.y; a0.z += v0.z; a0.w += v0.w;
      a1.x += v1.x; a1.y += v1.y; a1.z += v1.z; a1.w += v1.w;
      a2.x += v2.x; a2.y += v2.y; a2.z += v2.z; a2.w += v2.w;
      a3.x += v3.x; a3.y += v3.y; a3.z += v3.z; a3.w += v3.w;
      a4.x += v4.x; a4.y += v4.y; a4.z += v4.z; a4.w += v4.w;
      a5.x += v5.x; a5.y += v5.y; a5.z += v5.z; a5.w += v5.w;
      a6.x += v6.x; a6.y += v6.y; a6.z += v6.z; a6.w += v6.w;
      a7.x += v7.x; a7.y += v7.y; a7.z += v7.z; a7.w += v7.w;
    }
    for (; j + 4 <= nt; j += 4) {
      int t0 = __shfl(tk, j);
      int t1 = __shfl(tk, j + 1);
      int t2 = __shfl(tk, j + 2);
      int t3 = __shfl(tk, j + 3);
      float4 v0 = embv[(size_t)t0 * 64 + lane];
      float4 v1 = embv[(size_t)t1 * 64 + lane];
      float4 v2 = embv[(size_t)t2 * 64 + lane];
      float4 v3 = embv[(size_t)t3 * 64 + lane];
      a0.x += v0.x; a0.y += v0.y; a0.z += v0.z; a0.w += v0.w;
      a1.x += v1.x; a1.y += v1.y; a1.z += v1.z; a1.w += v1.w;
      a2.x += v2.x; a2.y += v2.y; a2.z += v2.z; a2.w += v2.w;
      a3.x += v3.x; a3.y += v3.y; a3.z += v3.z; a3.w += v3.w;
    }
    for (; j < nt; j++) {
      int t0 = __shfl(tk, j);
      float4 v0 = embv[(size_t)t0 * 64 + lane];
      a0.x += v0.x; a0.y += v0.y; a0.z += v0.z; a0.w += v0.w;
    }
  }
  float4 r;
  r.x = ((a0.x + a1.x) + (a2.x + a3.x)) + ((a4.x + a5.x) + (a6.x + a7.x));
  r.y = ((a0.y + a1.y) + (a2.y + a3.y)) + ((a4.y + a5.y) + (a6.y + a7.y));
  r.z = ((a0.z + a1.z) + (a2.z + a3.z)) + ((a4.z + a5.z) + (a6.z + a7.z));
  r.w = ((a0.w + a1.w) + (a2.w + a3.w)) + ((a4.w + a5.w) + (a6.w + a7.w));
  __shared__ float4 part[4][64];
  part[wv][lane] = r;
  __syncthreads();
  if (wv == 0) {
    float4 p1 = part[1][lane], p2 = part[2][lane], p3 = part[3][lane];
    const float inv = 1.0f / (float)len;
    r.x = ((r.x + p1.x) + (p2.x + p3.x)) * inv;
    r.y = ((r.y + p1.y) + (p2.y + p3.y)) * inv;
    r.z = ((r.z + p1.z) + (p2.z + p3.z)) * inv;
    r.w = ((r.w + p1.w) + (p2.w + p3.w)) * inv;
    ((float4*)pooled)[(size_t)row * 64 + lane] = r;
  }
}

// ---------------- K2: z = pooled @ W1^T + b1, fused per-block BN partials ------
__global__ __launch_bounds__(256) void gemm_stats_kernel(
    const float* __restrict__ pooled, const float* __restrict__ W1p,
    const float* __restrict__ b1, float* __restrict__ z,
    float* __restrict__ psum, float* __restrict__ psq) {
  __shared__ float4 SH[1024];   // 16 KB: pooled tile during loop, stats after
  const int tid = threadIdx.x;
  const int b0 = blockIdx.x * 16;
  const float4* pooled4 = (const float4*)pooled;
#pragma unroll
  for (int i = 0; i < 4; i++)
    SH[tid + i * 256] = pooled4[(size_t)b0 * 64 + tid + i * 256];
  __syncthreads();
  const int wv = tid >> 6, lane = tid & 63;
  const int r0 = wv * 4;
  float4 bb = ((const float4*)b1)[lane];
  float acc[4][4];
#pragma unroll
  for (int r = 0; r < 4; r++) {
    acc[r][0] = bb.x; acc[r][1] = bb.y; acc[r][2] = bb.z; acc[r][3] = bb.w;
  }
  const float4* w4 = (const float4*)W1p;
  for (int kb = 0; kb < 64; kb++) {
    float4 wk0 = w4[kb * 256 + lane * 4 + 0];
    float4 wk1 = w4[kb * 256 + lane * 4 + 1];
    float4 wk2 = w4[kb * 256 + lane * 4 + 2];
    float4 wk3 = w4[kb * 256 + lane * 4 + 3];
#pragma unroll
    for (int r = 0; r < 4; r++) {
      float4 p = SH[(r0 + r) * 64 + kb];   // wave-uniform -> LDS broadcast
      acc[r][0] += p.x * wk0.x + p.y * wk0.y + p.z * wk0.z + p.w * wk0.w;
      acc[r][1] += p.x * wk1.x + p.y * wk1.y + p.z * wk1.z + p.w * wk1.w;
      acc[r][2] += p.x * wk2.x + p.y * wk2.y + p.z * wk2.z + p.w * wk2.w;
      acc[r][3] += p.x * wk3.x + p.y * wk3.y + p.z * wk3.z + p.w * wk3.w;
    }
  }
  float4* z4 = (float4*)z;
  float4 s = make_float4(0.f, 0.f, 0.f, 0.f), q = s;
#pragma unroll
  for (int r = 0; r < 4; r++) {
    float4 o = make_float4(acc[r][0], acc[r][1], acc[r][2], acc[r][3]);
    z4[(size_t)(b0 + r0 + r) * 64 + lane] = o;
    s.x += o.x; s.y += o.y; s.z += o.z; s.w += o.w;
    q.x += o.x * o.x; q.y += o.y * o.y; q.z += o.z * o.z; q.w += o.w * o.w;
  }
  __syncthreads();   // done reading pooled tile; reuse SH for stats
  SH[wv * 64 + lane] = s;
  SH[256 + wv * 64 + lane] = q;
  __syncthreads();
  if (tid < 64) {
    float4 S = make_float4(0.f, 0.f, 0.f, 0.f), Q = S;
#pragma unroll
    for (int w = 0; w < 4; w++) {
      float4 a = SH[w * 64 + tid];
      float4 b = SH[256 + w * 64 + tid];
      S.x += a.x; S.y += a.y; S.z += a.z; S.w += a.w;
      Q.x += b.x; Q.y += b.y; Q.z += b.z; Q.w += b.w;
    }
    ((float4*)psum)[blockIdx.x * 64 + tid] = S;
    ((float4*)psq)[blockIdx.x * 64 + tid] = Q;
  }
}

// ---------------- K3: finalize BN: A[d] = gamma*rsqrt(var+eps), C[d] = beta-mu*A
__global__ __launch_bounds__(256) void bn_reduce_kernel(
    const float* __restrict__ psum, const float* __restrict__ psq,
    const float* __restrict__ gamma, const float* __restrict__ beta,
    float* __restrict__ A, float* __restrict__ C) {
  const int t = threadIdx.x;
  const int dd = t & 15, c = t >> 4;
  const int d = blockIdx.x * 16 + dd;
  float s = 0.f, q = 0.f;
#pragma unroll
  for (int i = 0; i < 16; i++) {
    int p = c * 16 + i;
    s += psum[p * 256 + d];
    q += psq[p * 256 + d];
  }
  __shared__ float sl[16][17], ql[16][17];
  sl[c][dd] = s; ql[c][dd] = q;
  __syncthreads();
  if (t < 16) {
    float S = 0.f, Q = 0.f;
#pragma unroll
    for (int c2 = 0; c2 < 16; c2++) { S += sl[c2][t]; Q += ql[c2][t]; }
    int dg = blockIdx.x * 16 + t;
    float m = S * (1.0f / 4096.0f);
    float v = Q * (1.0f / 4096.0f) - m * m;
    float a = gamma[dg] * rsqrtf(v + 1e-5f);
    A[dg] = a;
    C[dg] = beta[dg] - m * a;
  }
}

// ---------------- K4: BN-apply + ReLU + dot head + per-row BCE; wave per row ---
__global__ __launch_bounds__(256) void head_kernel(
    const float* __restrict__ z, const float* __restrict__ A,
    const float* __restrict__ C, const float* __restrict__ w2,
    const float* __restrict__ b2, const float* __restrict__ t,
    float* __restrict__ out, float* __restrict__ bce) {
  const int tid = threadIdx.x;
  const int wv = tid >> 6, lane = tid & 63;
  const int b = blockIdx.x * 4 + wv;
  float4 A4 = ((const float4*)A)[lane];
  float4 C4 = ((const float4*)C)[lane];
  float4 w24 = ((const float4*)w2)[lane];
  float4 zv = ((const float4*)z)[(size_t)b * 64 + lane];
  float h0 = fmaxf(A4.x * zv.x + C4.x, 0.f);
  float h1 = fmaxf(A4.y * zv.y + C4.y, 0.f);
  float h2 = fmaxf(A4.z * zv.z + C4.z, 0.f);
  float h3 = fmaxf(A4.w * zv.w + C4.w, 0.f);
  float part = h0 * w24.x + h1 * w24.y + h2 * w24.z + h3 * w24.w;
#pragma unroll
  for (int off = 32; off > 0; off >>= 1) part += __shfl_down(part, off);
  if (lane == 0) {
    float logit = part + b2[0];
    out[1 + b] = logit;
    float tb = t[b];
    bce[b] = fmaxf(logit, 0.f) - logit * tb + log1pf(expf(-fabsf(logit)));
  }
}

// ---------------- K5: final deterministic loss reduction ----------------------
__global__ __launch_bounds__(256) void loss_kernel(const float* __restrict__ bce,
                                                   float* __restrict__ out) {
  __shared__ float red[4];
  const int tid = threadIdx.x;
  float s = 0.f;
  for (int i = 0; i < 16; i++) s += bce[tid + i * 256];
#pragma unroll
  for (int off = 32; off > 0; off >>= 1) s += __shfl_down(s, off);
  if ((tid & 63) == 0) red[tid >> 6] = s;
  __syncthreads();
  if (tid == 0) out[0] = (red[0] + red[1] + red[2] + red[3]) * (1.0f / 4096.0f);
}

extern "C" void kernel_launch(void* const* d_in, const int* in_sizes, int n_in,
                              void* d_out, int out_size, void* d_ws, size_t ws_size,
                              hipStream_t stream) {
  const int* tokens = (const int*)d_in[0];
  const int* lengths = (const int*)d_in[1];
  const float* t = (const float*)d_in[2];
  const float* emb = (const float*)d_in[3];
  const float* W1 = (const float*)d_in[4];
  const float* b1 = (const float*)d_in[5];
  const float* gamma = (const float*)d_in[6];
  const float* beta = (const float*)d_in[7];
  const float* w2 = (const float*)d_in[8];
  const float* b2 = (const float*)d_in[9];
  float* out = (float*)d_out;

  float* wsf = (float*)d_ws;
  float* pooled = wsf;                 // 1,048,576 floats
  float* z = wsf + 1048576;            // 1,048,576
  float* W1p = wsf + 2097152;          // 65,536
  float* psum = wsf + 2162688;         // 65,536 (256 blocks x 256 dims)
  float* psq = wsf + 2228224;          // 65,536
  float* A = wsf + 2293760;            // 256
  float* C = wsf + 2294016;            // 256
  float* bce = wsf + 2294272;          // 4,096
  // total ~8.8 MiB of d_ws

  pool_pack_kernel<<<4096, 256, 0, stream>>>(tokens, lengths, emb, pooled, W1, W1p);
  gemm_stats_kernel<<<256, 256, 0, stream>>>(pooled, W1p, b1, z, psum, psq);
  bn_reduce_kernel<<<16, 256, 0, stream>>>(psum, psq, gamma, beta, A, C);
  head_kernel<<<1024, 256, 0, stream>>>(z, A, C, w2, b2, t, out, bce);
  loss_kernel<<<1, 256, 0, stream>>>(bce, out);
}